// Round 14
// baseline (204.524 us; speedup 1.0000x reference)
//
#include <hip/hip_runtime.h>
#include <hip/hip_bf16.h>

// Cholesky-QR Gram-Schmidt, 16 vectors x dim-256, 32768 rows, fp32,
// layout (16, 32768, 256).
//
// R14 = R13 with PLAIN stores (A/B isolating the nontemporal-store change;
// theory: NT bypasses L3 write-combining and exposes raw HBM turnaround,
// costing ~2% — the rest of R13's trim is kept):
//  - single fp32 LDS staging buffer (16.6 KB), bf16 hi/lo split at frag
//    read -> half the ds_writes of R5-best, one barrier total.
//  - G redistribution via 16 __shfl (no G scatter buffer, no 2nd barrier).
//  - fused right-looking Cholesky + forward substitution, stores spread
//    across the solve. Math identical since R5 (absmax 1.95e-3).

constexpr int NM   = 16;     // vectors per row
constexpr int NR   = 32768;  // rows
constexpr int D4   = 64;     // float4 per vector
constexpr int FROW = 260;    // floats per LDS vector row (256 + 4 pad: 2-way banks)

typedef __attribute__((ext_vector_type(8))) short short8v;  // 8 x bf16
typedef __attribute__((ext_vector_type(4))) float f32x4;

__device__ __forceinline__ float rl(float x, int lane) {
    return __builtin_bit_cast(float,
        __builtin_amdgcn_readlane(__builtin_bit_cast(int, x), lane));
}

// 8 fp32 -> bf16 hi + bf16 lo fragments (hi = bf16(f), lo = bf16(f - hi)).
__device__ __forceinline__ void cvt8(const float4& f0, const float4& f1,
                                     short8v& ah, short8v& al) {
    float f[8] = {f0.x, f0.y, f0.z, f0.w, f1.x, f1.y, f1.z, f1.w};
#pragma unroll
    for (int j = 0; j < 8; ++j) {
        unsigned short hb =
            __builtin_bit_cast(unsigned short, __float2bfloat16(f[j]));
        ah[j] = (short)hb;
        float hv = __builtin_bit_cast(float, (unsigned int)hb << 16);  // exact
        al[j] = (short)__builtin_bit_cast(unsigned short,
                                          __float2bfloat16(f[j] - hv));
    }
}

__global__ __launch_bounds__(64) void gs_kernel(const float* __restrict__ x,
                                                float* __restrict__ out) {
    __shared__ __align__(16) float sm[NM * FROW];   // 16640 B

    const int lane = threadIdx.x;
    const int row  = blockIdx.x;
    const int vec  = lane & 15;   // vector owned in the MFMA fragment
    const int kgrp = lane >> 4;   // k-group 0..3

    const float4* __restrict__ xi = reinterpret_cast<const float4*>(x);
    float4* __restrict__ oo       = reinterpret_cast<float4*>(out);

    // Coalesced load: lane l owns elements [4l, 4l+4) of every vector.
    float4 v[NM];
#pragma unroll
    for (int i = 0; i < NM; ++i)
        v[i] = xi[(size_t)(i * NR + row) * D4 + lane];

    // Stage fp32 to LDS (16 x ds_write_b128).
#pragma unroll
    for (int i = 0; i < NM; ++i)
        *reinterpret_cast<float4*>(&sm[i * FROW + 4 * lane]) = v[i];
    __syncthreads();

    // G = V V^T via MFMA (bf16 hi/lo split at read, 3 terms).
    f32x4 g = {0.0f, 0.0f, 0.0f, 0.0f};
#pragma unroll
    for (int c = 0; c < 8; ++c) {
        const int off = vec * FROW + c * 32 + kgrp * 8;
        float4 f0 = *reinterpret_cast<const float4*>(&sm[off]);
        float4 f1 = *reinterpret_cast<const float4*>(&sm[off + 4]);
        short8v ah, al;
        cvt8(f0, f1, ah, al);
        g = __builtin_amdgcn_mfma_f32_16x16x32_bf16(ah, ah, g, 0, 0, 0);
        g = __builtin_amdgcn_mfma_f32_16x16x32_bf16(ah, al, g, 0, 0, 0);
        g = __builtin_amdgcn_mfma_f32_16x16x32_bf16(al, ah, g, 0, 0, 0);
    }

    // a[n] = G[vec][n] via shfl (C/D map orientation-proof by G's symmetry).
    float a[NM];
#pragma unroll
    for (int n = 0; n < NM; ++n)
        a[n] = __shfl(g[n & 3], vec + 16 * (n >> 2), 64);

    // Fused right-looking Cholesky + forward substitution.
#pragma unroll
    for (int j = 0; j < NM; ++j) {
        float p   = rl(a[j], j);                    // pivot = ||w_j||^2
        float inv = (p > 0.0f) ? rsqrtf(p) : 0.0f;  // safe-div
        v[j].x *= inv; v[j].y *= inv; v[j].z *= inv; v[j].w *= inv;   // q_j
        oo[(size_t)(j * NR + row) * D4 + lane] = v[j];
        a[j] *= inv;                                // column j of L
#pragma unroll
        for (int t = j + 1; t < NM; ++t) {
            float u = rl(a[j], t);                  // L[t][j] = <v_t, q_j>
            a[t]  = fmaf(-u, a[j], a[t]);           // Cholesky trailing update
            v[t].x = fmaf(-u, v[j].x, v[t].x);      // v_t -= L[t][j] * q_j
            v[t].y = fmaf(-u, v[j].y, v[t].y);
            v[t].z = fmaf(-u, v[j].z, v[t].z);
            v[t].w = fmaf(-u, v[j].w, v[t].w);
        }
    }
}

extern "C" void kernel_launch(void* const* d_in, const int* in_sizes, int n_in,
                              void* d_out, int out_size, void* d_ws, size_t ws_size,
                              hipStream_t stream) {
    const float* x = (const float*)d_in[0];
    float* out     = (float*)d_out;
    dim3 grid(NR);     // one wave per row
    dim3 block(64);
    hipLaunchKernelGGL(gs_kernel, grid, block, 0, stream, x, out);
}